// Round 6
// baseline (283.776 us; speedup 1.0000x reference)
//
#include <hip/hip_runtime.h>

// Problem constants (from reference): H=256, N=100000, B=8, S=128 -> T=1024
#define T_ROWS 1024
#define H_DIM  256
#define N_COLS 100000
#define QF     127.0f

// swapped-operand gemm geometry: block = 128 n x 256 t (8 iters of 32 t)
#define BNW   128                  // n per block (4 waves x 32)
#define NB3   782                  // ceil(100000/128), last block 32 cols
#define TCH   4                    // t-chunks of 256
#define GRID3 (NB3 * TCH)          // 3128 = 8*391

typedef __attribute__((ext_vector_type(4))) float f32x4;
typedef __attribute__((ext_vector_type(8))) short short8;   // 8 bf16 (MFMA A/B frag)
typedef __attribute__((ext_vector_type(4))) short short4v;  // 4 bf16 = 8B

__device__ __forceinline__ float wave_absmax(float v) {
#pragma unroll
    for (int off = 32; off > 0; off >>= 1)
        v = fmaxf(v, __shfl_xor(v, off, 64));
    return v;
}

// Exact f32 -> bf16 for integer-valued floats |q| <= 127: truncation is exact.
__device__ __forceinline__ short f32_to_bf16_exact(float f) {
    unsigned u = __builtin_bit_cast(unsigned, f);
    return (short)(u >> 16);
}

// ---------------- Kernel 1: per-row quantize X -> integer-valued bf16 + absmax
__global__ __launch_bounds__(256) void quant_x(const float* __restrict__ X,
                                               short* __restrict__ x8,
                                               float* __restrict__ sx) {
    const int w = threadIdx.x >> 6, l = threadIdx.x & 63;
    const int row = blockIdx.x * 4 + w;
    const float4 v = ((const float4*)X)[row * 64 + l];
    float amax = fmaxf(fmaxf(fabsf(v.x), fabsf(v.y)), fmaxf(fabsf(v.z), fabsf(v.w)));
    amax = wave_absmax(amax);
    const float scale = (amax == 0.f) ? 1.f : amax;
    const float qs = QF / scale;
    short4v q;
    q.x = f32_to_bf16_exact(rintf(v.x * qs));
    q.y = f32_to_bf16_exact(rintf(v.y * qs));
    q.z = f32_to_bf16_exact(rintf(v.z * qs));
    q.w = f32_to_bf16_exact(rintf(v.w * qs));
    *(short4v*)(x8 + row * H_DIM + l * 4) = q;
    if (l == 0) sx[row] = amax;
}

// ---------------- Kernel 2: per-row quantize W -> integer-valued bf16 + absmax
__global__ __launch_bounds__(256) void quant_w(const float* __restrict__ W,
                                               short* __restrict__ w8,
                                               float* __restrict__ sw) {
    const int w = threadIdx.x >> 6, l = threadIdx.x & 63;
    const int row = blockIdx.x * 4 + w;            // N = 25000*4 exactly
    const float4 v = ((const float4*)W)[(size_t)row * 64 + l];
    float amax = fmaxf(fmaxf(fabsf(v.x), fabsf(v.y)), fmaxf(fabsf(v.z), fabsf(v.w)));
    amax = wave_absmax(amax);
    const float scale = (amax == 0.f) ? 1.f : amax;
    const float qs = QF / scale;
    short4v q;
    q.x = f32_to_bf16_exact(rintf(v.x * qs));
    q.y = f32_to_bf16_exact(rintf(v.y * qs));
    q.z = f32_to_bf16_exact(rintf(v.z * qs));
    q.w = f32_to_bf16_exact(rintf(v.w * qs));
    *(short4v*)(w8 + (size_t)row * H_DIM + l * 4) = q;
    if (l == 0) sw[row] = amax;
}

// ---------------- swapped-operand GEMM: no LDS, no barriers
// mfma(B-frag, A-frag) -> D[n][t]: col=lane&15 -> t, row=(lane>>4)*4+r -> n.
// Each lane's 4 acc regs = 4 CONSECUTIVE n at one t -> direct float4 store;
// nf=0/1 stores form one aligned 128B line, merged in L2 (R5: WRITE=400MB).
struct ABuf {
    short8 a[2][8];   // [mr][kk]
    float  sxv[2];    // sx for the two t-subtiles
};

__device__ __forceinline__ void load_a(ABuf& ab, const short* __restrict__ x8,
                                       const float* __restrict__ sx,
                                       int t0, int lm, int lg) {
#pragma unroll
    for (int mr = 0; mr < 2; ++mr) {
        const short* A = x8 + (t0 + mr * 16 + lm) * H_DIM + 8 * lg;
#pragma unroll
        for (int kk = 0; kk < 8; ++kk)
            ab.a[mr][kk] = *(const short8*)(A + kk * 32);
        ab.sxv[mr] = sx[t0 + mr * 16 + lm];
    }
}

__device__ __forceinline__ void mfma_tile(f32x4 (&acc)[2][2], const ABuf& ab,
                                          const short8 (&bfr)[2][8]) {
#pragma unroll
    for (int kk = 0; kk < 8; ++kk)
#pragma unroll
        for (int mr = 0; mr < 2; ++mr)
#pragma unroll
            for (int nf = 0; nf < 2; ++nf)
                acc[mr][nf] = __builtin_amdgcn_mfma_f32_16x16x32_bf16(
                    bfr[nf][kk], ab.a[mr][kk], acc[mr][nf], 0, 0, 0);
}

__device__ __forceinline__ void store_tile(const f32x4 (&acc)[2][2], const ABuf& ab,
                                           const f32x4 (&sw4)[2], const f32x4 (&b4)[2],
                                           const bool (&okn)[2],
                                           float* __restrict__ out,
                                           int t0, int lm, int lg, int nwave) {
    const float invqq = 1.0f / (QF * QF);
#pragma unroll
    for (int mr = 0; mr < 2; ++mr) {
        const int t = t0 + mr * 16 + lm;
        const float s0 = ab.sxv[mr] * invqq;
#pragma unroll
        for (int nf = 0; nf < 2; ++nf) {
            if (okn[nf]) {
                f32x4 o;
#pragma unroll
                for (int r = 0; r < 4; ++r)
                    o[r] = acc[mr][nf][r] * (s0 * sw4[nf][r]) + b4[nf][r];
                *(f32x4*)(out + (size_t)t * N_COLS + nwave + nf * 16 + lg * 4) = o;
            }
        }
    }
}

__global__ __launch_bounds__(256, 4) void gemm_swap(const short* __restrict__ x8,
                                                    const float* __restrict__ sx,
                                                    const short* __restrict__ w8,
                                                    const float* __restrict__ sw,
                                                    const float* __restrict__ bias,
                                                    float* __restrict__ out) {
    // ---- THE R6 EXPERIMENT: row-major-per-XCD write order ----
    // HW dispatch round-robins XCD = bid & 7 (m09/m157). Map so each XCD owns
    // a fixed 256-row t-band (tc = xcd>>1) and, within the XCD, temporally
    // consecutive blocks sweep n ascending (nb = (xcd&1)*391 + (bid>>3)).
    // Per XCD the write stream becomes 256 quasi-sequential row-streams
    // (DRAM page hits), instead of the 400KB-stride column walk of R5.
    const int bid = blockIdx.x;
    const int xcd = bid & 7;
    const int j   = bid >> 3;              // 0..390, temporal order within XCD
    const int tc  = xcd >> 1;              // t-chunk of 256 rows
    const int nb  = (xcd & 1) * 391 + j;   // n sweeps fastest within each XCD

    const int w = threadIdx.x >> 6, l = threadIdx.x & 63;
    const int lg = l >> 4, lm = l & 15;
    const int nwave = nb * BNW + w * 32;   // this wave's 32 n-columns
    const int tbase = tc * 256;

    // B-frags (persist in regs, reused across all 8 t-iters) + store-side scales
    short8 bfr[2][8];
    f32x4 sw4[2], b4[2];
    bool okn[2];
#pragma unroll
    for (int nf = 0; nf < 2; ++nf) {
        const int nrow = nwave + nf * 16 + lm;
        const int nc = nrow < N_COLS ? nrow : N_COLS - 1;
        const short* B = w8 + (size_t)nc * H_DIM + 8 * lg;
#pragma unroll
        for (int kk = 0; kk < 8; ++kk)
            bfr[nf][kk] = *(const short8*)(B + kk * 32);
        const int ns = nwave + nf * 16 + lg * 4;   // base n of this lane's float4
        okn[nf] = ns < N_COLS;                     // N%16==0 -> whole float4 in/out
        const int nsc = okn[nf] ? ns : 0;
        sw4[nf] = *(const f32x4*)(sw + nsc);
        b4[nf]  = *(const f32x4*)(bias + nsc);
    }

    // 8 t-iterations, single A buffer: x8 is L2/L3-resident (512KB, every
    // block reads it) so load latency is ~200cy, hidden by TLP.
    ABuf ab;
#pragma unroll 1
    for (int ii = 0; ii < 8; ++ii) {
        const int t0 = tbase + ii * 32;
        load_a(ab, x8, sx, t0, lm, lg);
        f32x4 acc[2][2];
#pragma unroll
        for (int mr = 0; mr < 2; ++mr)
#pragma unroll
            for (int nf = 0; nf < 2; ++nf) acc[mr][nf] = (f32x4){0.f, 0.f, 0.f, 0.f};
        mfma_tile(acc, ab, bfr);
        store_tile(acc, ab, sw4, b4, okn, out, t0, lm, lg, nwave);
    }
}

// ---------------- Fallback fused kernel (used only if ws too small for w8)
__global__ __launch_bounds__(256, 3) void gemm_main(const float* __restrict__ W,
                                                    const float* __restrict__ bias,
                                                    const short* __restrict__ x8,
                                                    const float* __restrict__ sx,
                                                    float* __restrict__ out) {
    __shared__ short wlds[64 * H_DIM];
    __shared__ float sw_lds[64];

    const int tid = threadIdx.x;
    const int w = tid >> 6, l = tid & 63;
    const int n0 = blockIdx.x * 64;

    const float4* W4 = (const float4*)W;
#pragma unroll 4
    for (int r = 0; r < 16; ++r) {
        const int row = r * 4 + w;
        const int n = n0 + row;
        float4 v;
        if (n < N_COLS) v = W4[(size_t)n * 64 + l];
        else { v.x = 0.f; v.y = 0.f; v.z = 0.f; v.w = 0.f; }
        float amax = fmaxf(fmaxf(fabsf(v.x), fabsf(v.y)), fmaxf(fabsf(v.z), fabsf(v.w)));
        amax = wave_absmax(amax);
        const float scale = (amax == 0.f) ? 1.f : amax;
        const float qs = QF / scale;
        short4v q;
        q.x = f32_to_bf16_exact(rintf(v.x * qs));
        q.y = f32_to_bf16_exact(rintf(v.y * qs));
        q.z = f32_to_bf16_exact(rintf(v.z * qs));
        q.w = f32_to_bf16_exact(rintf(v.w * qs));
        const int sidx = row * H_DIM + ((l * 4) ^ ((row & 7) << 3));
        *(short4v*)(wlds + sidx) = q;
        if (l == 0) sw_lds[row] = amax;
    }
    __syncthreads();

    const int wm = w >> 1, wn = w & 1;
    const int lg = l >> 4, lm = l & 15;

    float swv[2], bv[2];
#pragma unroll
    for (int nr = 0; nr < 2; ++nr) {
        const int ncol = wn * 32 + nr * 16 + lm;
        swv[nr] = sw_lds[ncol];
        const int n = n0 + ncol;
        bv[nr] = (n < N_COLS) ? bias[n] : 0.f;
    }

    short8 bfr[2][8];
#pragma unroll
    for (int nr = 0; nr < 2; ++nr) {
        const int row = wn * 32 + nr * 16 + lm;
#pragma unroll
        for (int kk = 0; kk < 8; ++kk) {
            const int sidx = row * H_DIM + ((kk * 32 + 8 * lg) ^ ((row & 7) << 3));
            bfr[nr][kk] = *(const short8*)(wlds + sidx);
        }
    }

    const float invqq = 1.0f / (QF * QF);
    const f32x4 zero4 = {0.f, 0.f, 0.f, 0.f};

    for (int tt = 0; tt < 16; ++tt) {
        const int t0 = tt * 64;
        f32x4 acc[2][2];
        acc[0][0] = zero4; acc[0][1] = zero4; acc[1][0] = zero4; acc[1][1] = zero4;

        const short* abase0 = x8 + (t0 + wm * 32 + lm) * H_DIM + 8 * lg;
#pragma unroll
        for (int kk = 0; kk < 8; ++kk) {
            const short8 a0 = *(const short8*)(abase0 + kk * 32);
            const short8 a1 = *(const short8*)(abase0 + 16 * H_DIM + kk * 32);
            acc[0][0] = __builtin_amdgcn_mfma_f32_16x16x32_bf16(a0, bfr[0][kk], acc[0][0], 0, 0, 0);
            acc[0][1] = __builtin_amdgcn_mfma_f32_16x16x32_bf16(a0, bfr[1][kk], acc[0][1], 0, 0, 0);
            acc[1][0] = __builtin_amdgcn_mfma_f32_16x16x32_bf16(a1, bfr[0][kk], acc[1][0], 0, 0, 0);
            acc[1][1] = __builtin_amdgcn_mfma_f32_16x16x32_bf16(a1, bfr[1][kk], acc[1][1], 0, 0, 0);
        }

#pragma unroll
        for (int mr = 0; mr < 2; ++mr) {
            const int trow = t0 + wm * 32 + mr * 16 + lg * 4;
#pragma unroll
            for (int r = 0; r < 4; ++r) {
                const int t = trow + r;
                const float sxv = sx[t];
#pragma unroll
                for (int nr = 0; nr < 2; ++nr) {
                    const int n = n0 + wn * 32 + nr * 16 + lm;
                    if (n < N_COLS)
                        out[(size_t)t * N_COLS + n] =
                            acc[mr][nr][r] * ((sxv * swv[nr]) * invqq) + bv[nr];
                }
            }
        }
    }
}

extern "C" void kernel_launch(void* const* d_in, const int* in_sizes, int n_in,
                              void* d_out, int out_size, void* d_ws, size_t ws_size,
                              hipStream_t stream) {
    const float* X    = (const float*)d_in[0];   // [8,128,256] f32
    const float* W    = (const float*)d_in[1];   // [100000,256] f32
    const float* bias = (const float*)d_in[2];   // [100000] f32
    float* out = (float*)d_out;                  // [1024,100000] f32

    const size_t x8_bytes = (size_t)T_ROWS * H_DIM * 2;
    const size_t sx_bytes = (size_t)T_ROWS * 4;
    const size_t w8_bytes = (size_t)N_COLS * H_DIM * 2;
    const size_t sw_bytes = (size_t)N_COLS * 4;
    const size_t need = x8_bytes + sx_bytes + w8_bytes + sw_bytes;

    short* x8 = (short*)d_ws;
    float* sx = (float*)((char*)d_ws + x8_bytes);

    quant_x<<<T_ROWS / 4, 256, 0, stream>>>(X, x8, sx);

    if (ws_size >= need) {
        short* w8 = (short*)((char*)d_ws + x8_bytes + sx_bytes);
        float* sw = (float*)((char*)d_ws + x8_bytes + sx_bytes + w8_bytes);
        quant_w<<<N_COLS / 4, 256, 0, stream>>>(W, w8, sw);
        gemm_swap<<<GRID3, 256, 0, stream>>>(x8, sx, w8, sw, bias, out);
    } else {
        gemm_main<<<(N_COLS + 63) / 64, 256, 0, stream>>>(W, bias, x8, sx, out);
    }
}

// Round 7
// 177.705 us; speedup vs baseline: 1.5969x; 1.5969x over previous
//
#include <hip/hip_runtime.h>

// Problem constants (from reference): H=256, N=100000, B=8, S=128 -> T=1024
#define T_ROWS 1024
#define H_DIM  256
#define N_COLS 100000
#define QF     127.0f

#define NB16   6250                // N/16 (exact)
#define BNW    128                 // n per gemm block (4 waves x 32)
#define NB3    782                 // ceil(N/128), last block 32 cols
#define TCH    4                   // t-chunks of 256
#define GRID3  (NB3 * TCH)         // 3128 = 8*391 -> bijective XCD swizzle

typedef __attribute__((ext_vector_type(4))) float f32x4;
typedef __attribute__((ext_vector_type(2))) float f32x2;
typedef __attribute__((ext_vector_type(8))) short short8;   // 8 bf16 (MFMA frag)
typedef __attribute__((ext_vector_type(4))) short short4v;  // 4 bf16 = 8B

// Exact f32 -> bf16 for integer-valued floats |q| <= 127: truncation is exact.
__device__ __forceinline__ short f32_to_bf16_exact(float f) {
    unsigned u = __builtin_bit_cast(unsigned, f);
    return (short)(u >> 16);
}

__device__ __forceinline__ float wave_absmax64(float v) {
#pragma unroll
    for (int off = 32; off > 0; off >>= 1)
        v = fmaxf(v, __shfl_xor(v, off, 64));
    return v;
}

// ---------------- Kernel 1: quantize X -> FRAG-MAJOR bf16 x8F + absmax
// x8F layout: [tile(32)][kk(8)][mr(2)][lane(64)][j(8)] shorts.
// Element (t,k): tile=t>>5, mr=(t>>4)&1, lm=t&15, kk=k>>5, lg=(k&31)>>3, j=k&7,
// lane=lg*16+lm. A wave's frag load is then 64 lanes x 16B CONTIGUOUS.
__global__ __launch_bounds__(256) void quant_x(const float* __restrict__ X,
                                               short* __restrict__ x8F,
                                               float* __restrict__ sx) {
    const int w = threadIdx.x >> 6, l = threadIdx.x & 63;
    const int row = blockIdx.x * 4 + w;                 // t
    const float4 v = ((const float4*)X)[row * 64 + l];  // coalesced 16B/lane
    float amax = fmaxf(fmaxf(fabsf(v.x), fabsf(v.y)), fmaxf(fabsf(v.z), fabsf(v.w)));
    amax = wave_absmax64(amax);
    const float scale = (amax == 0.f) ? 1.f : amax;
    const float qs = QF / scale;
    short4v q;
    q.x = f32_to_bf16_exact(rintf(v.x * qs));
    q.y = f32_to_bf16_exact(rintf(v.y * qs));
    q.z = f32_to_bf16_exact(rintf(v.z * qs));
    q.w = f32_to_bf16_exact(rintf(v.w * qs));
    // k = 4l..4l+3 -> same (kk,lg), j = (4l)&7 in {0,4}: one contiguous 8B write
    const int tile = row >> 5, mr = (row >> 4) & 1, lm = row & 15;
    const int kk = l >> 3, lg = (l >> 1) & 3, j = (l & 1) * 4;
    const int lane = lg * 16 + lm;
    *(short4v*)(x8F + (((tile * 8 + kk) * 2 + mr) * 64 + lane) * 8 + j) = q;
    if (l == 0) sx[row] = amax;
}

// ---------------- Kernel 2: quantize W -> FRAG-MAJOR bf16 w8F + absmax
// w8F layout: [nb16(6250)][kk(8)][lane(64)][j(8)] shorts (8KB per 16-row block).
// Block: 256 thr <-> 16 rows. Reads coalesced; LDS transpose; 8KB contiguous out.
__global__ __launch_bounds__(256) void quant_w(const float* __restrict__ W,
                                               short* __restrict__ w8F,
                                               float* __restrict__ sw) {
    __shared__ short tile[16 * 256];
    const int tid = threadIdx.x;
    const int nb16 = blockIdx.x;                 // 0..6249
    const int r16 = tid >> 4, c16 = tid & 15;
    const int n = nb16 * 16 + r16;
    const float4* src = (const float4*)(W + (size_t)n * H_DIM + c16 * 16);
    float4 v[4];
    float amax = 0.f;
#pragma unroll
    for (int i = 0; i < 4; ++i) {
        v[i] = src[i];
        amax = fmaxf(amax, fmaxf(fmaxf(fabsf(v[i].x), fabsf(v[i].y)),
                                 fmaxf(fabsf(v[i].z), fabsf(v[i].w))));
    }
    // reduce absmax across the row's 16 threads (lane group of 16)
#pragma unroll
    for (int off = 8; off > 0; off >>= 1)
        amax = fmaxf(amax, __shfl_xor(amax, off, 64));
    const float scale = (amax == 0.f) ? 1.f : amax;
    const float qs = QF / scale;
    short qv[16];
#pragma unroll
    for (int i = 0; i < 4; ++i) {
        qv[i * 4 + 0] = f32_to_bf16_exact(rintf(v[i].x * qs));
        qv[i * 4 + 1] = f32_to_bf16_exact(rintf(v[i].y * qs));
        qv[i * 4 + 2] = f32_to_bf16_exact(rintf(v[i].z * qs));
        qv[i * 4 + 3] = f32_to_bf16_exact(rintf(v[i].w * qs));
    }
    *(short8*)&tile[r16 * 256 + c16 * 16]     = *(short8*)&qv[0];
    *(short8*)&tile[r16 * 256 + c16 * 16 + 8] = *(short8*)&qv[8];
    if (c16 == 0) sw[n] = amax;
    __syncthreads();
    // frag-major out: thread -> (kk = tid>>5, lanes 2i2, 2i2+1), 32B contiguous
    const int kk = tid >> 5, i2 = tid & 31;
    const int L0 = 2 * i2, L1 = L0 + 1;
    short* dst = w8F + ((size_t)nb16 * 8 + kk) * 512 + i2 * 16;
    *(short8*)(dst)     = *(short8*)&tile[(L0 & 15) * 256 + kk * 32 + (L0 >> 4) * 8];
    *(short8*)(dst + 8) = *(short8*)&tile[(L1 & 15) * 256 + kk * 32 + (L1 >> 4) * 8];
}

// ---------------- Kernel 3: fully-contiguous-VMEM GEMM
// Swapped MFMA (D[n][t]). A/B frag loads: 1KB unit-stride per instruction
// (frag-major x8F/w8F). Epilogue: raw acc -> XOR-swizzled LDS (2x16KB dbuf,
// one barrier/iter) -> per-row 512B unit-stride float2 stores.
__global__ __launch_bounds__(256, 3) void gemm_ctg(const short* __restrict__ x8F,
                                                   const float* __restrict__ sx,
                                                   const short* __restrict__ w8F,
                                                   const float* __restrict__ sw,
                                                   const float* __restrict__ bias,
                                                   float* __restrict__ out) {
    __shared__ float olds[2][32 * 128];   // 2 x 16KB

    // bijective XCD swizzle (3128 = 8*391); tc-inner -> w8 panel L2 reuse
    const int bid = blockIdx.x;
    const int s = (bid & 7) * (GRID3 / 8) + (bid >> 3);
    const int nb = s >> 2;                 // 0..781
    const int tc = s & 3;                  // t-chunk of 256 rows
    const int w = threadIdx.x >> 6, l = threadIdx.x & 63;
    const int lg = l >> 4, lm = l & 15;
    const int tbase = tc * 256;
    const int nb16w = nb * 8 + w * 2;      // this wave's first 16-row n-block

    // B-frags: 16 x 1KB contiguous loads, persist in regs across all 8 iters
    short8 bfr[2][8];
#pragma unroll
    for (int nf = 0; nf < 2; ++nf) {
        const int nbc = (nb16w + nf < NB16) ? (nb16w + nf) : (NB16 - 1);
        const short* B = w8F + (size_t)nbc * 4096 + l * 8;
#pragma unroll
        for (int kk = 0; kk < 8; ++kk)
            bfr[nf][kk] = *(const short8*)(B + kk * 512);
    }

    // store-side per-lane constants: this lane stores cols colb, colb+1 (all rows)
    const int colb = nb * 128 + 2 * l;
    const bool okc = colb < N_COLS;        // N even -> float2 fully in/out
    const int colc = okc ? colb : 0;
    const f32x2 sw2 = *(const f32x2*)(sw + colc);
    const f32x2 b2  = *(const f32x2*)(bias + colc);
    const float invqq = 1.0f / (QF * QF);

#pragma unroll 1
    for (int ii = 0; ii < 8; ++ii) {
        const int t0 = tbase + ii * 32;
        const int tile = t0 >> 5;
        f32x4 acc[2][2];
#pragma unroll
        for (int mr = 0; mr < 2; ++mr)
#pragma unroll
            for (int nf = 0; nf < 2; ++nf) acc[mr][nf] = (f32x4){0.f, 0.f, 0.f, 0.f};

#pragma unroll
        for (int mr = 0; mr < 2; ++mr) {
            short8 a[8];
#pragma unroll
            for (int kk = 0; kk < 8; ++kk)      // 1KB contiguous per load
                a[kk] = *(const short8*)(x8F + (size_t)((tile * 8 + kk) * 2 + mr) * 512 + l * 8);
#pragma unroll
            for (int kk = 0; kk < 8; ++kk) {
                acc[mr][0] = __builtin_amdgcn_mfma_f32_16x16x32_bf16(bfr[0][kk], a[kk], acc[mr][0], 0, 0, 0);
                acc[mr][1] = __builtin_amdgcn_mfma_f32_16x16x32_bf16(bfr[1][kk], a[kk], acc[mr][1], 0, 0, 0);
            }
        }

        // raw acc -> LDS, XOR-swizzled cols (bank spread)
        float* ob = olds[ii & 1];
#pragma unroll
        for (int mr = 0; mr < 2; ++mr) {
            const int trow = mr * 16 + lm;
#pragma unroll
            for (int nf = 0; nf < 2; ++nf) {
                const int c = (w * 32 + nf * 16 + lg * 4) ^ ((trow & 7) << 2);
                *(f32x4*)(ob + trow * 128 + c) = acc[mr][nf];
            }
        }
        __syncthreads();

        // store phase: wave w stores rows w*8..w*8+7; per row one 512B
        // unit-stride segment (64 lanes x float2), dequant on read
#pragma unroll
        for (int i = 0; i < 8; ++i) {
            const int row = w * 8 + i;
            const int t = t0 + row;
            const float s0 = sx[t] * invqq;                  // wave-uniform
            const f32x2 v = *(const f32x2*)(ob + row * 128 + ((2 * l) ^ ((row & 7) << 2)));
            if (okc) {
                f32x2 o;
                o[0] = v[0] * (s0 * sw2[0]) + b2[0];
                o[1] = v[1] * (s0 * sw2[1]) + b2[1];
                *(f32x2*)(out + (size_t)t * N_COLS + colb) = o;
            }
        }
        // next iter writes the other LDS buffer; the following barrier
        // guarantees reads of this buffer finished before it's overwritten
    }
}

extern "C" void kernel_launch(void* const* d_in, const int* in_sizes, int n_in,
                              void* d_out, int out_size, void* d_ws, size_t ws_size,
                              hipStream_t stream) {
    const float* X    = (const float*)d_in[0];   // [8,128,256] f32
    const float* W    = (const float*)d_in[1];   // [100000,256] f32
    const float* bias = (const float*)d_in[2];   // [100000] f32
    float* out = (float*)d_out;                  // [1024,100000] f32

    // ws layout: x8F 512KB | sx 4KB | w8F 51.2MB | sw 400KB  (proven to fit)
    const size_t x8_bytes = (size_t)T_ROWS * H_DIM * 2;
    const size_t sx_bytes = (size_t)T_ROWS * 4;
    const size_t w8_bytes = (size_t)N_COLS * H_DIM * 2;

    short* x8F = (short*)d_ws;
    float* sx  = (float*)((char*)d_ws + x8_bytes);
    short* w8F = (short*)((char*)d_ws + x8_bytes + sx_bytes);
    float* sw  = (float*)((char*)d_ws + x8_bytes + sx_bytes + w8_bytes);

    quant_x<<<T_ROWS / 4, 256, 0, stream>>>(X, x8F, sx);
    quant_w<<<NB16, 256, 0, stream>>>(W, w8F, sw);
    gemm_ctg<<<GRID3, 256, 0, stream>>>(x8F, sx, w8F, sw, bias, out);
}